// Round 7
// baseline (471.078 us; speedup 1.0000x reference)
//
#include <hip/hip_runtime.h>
#include <cstdint>
#include <cstddef>

#define NS 512
#define NT 384
#define CZ 128

typedef __bf16 bf16x8 __attribute__((ext_vector_type(8)));
typedef __bf16 bf16x4 __attribute__((ext_vector_type(4)));
typedef float floatx16 __attribute__((ext_vector_type(16)));
typedef float floatx4 __attribute__((ext_vector_type(4)));

// Workspace layouts (bf16 element units):
//   A_t[rb(96)][kc(64)][r(128)][e(8)]   panel = 65536 elems (128 rows, k=s)
//   B_t[pb(48)][kc(64)][r(256)][e(8)]   panel = 131072 elems
//   WT [e(128)][k(1024)]  k = (c>>4)*512 + d*16 + (c&15)
// k index = s;  kc = s>>3, e = s&7.  A-row m = i*32+c, B-row n = j*32+d.

// ---------------------------------------------------------------------------
__global__ __launch_bounds__(256) void prep_wout(const float* __restrict__ Wout,
                                                 __bf16* __restrict__ WT) {
  const int idx = blockIdx.x * 256 + threadIdx.x;  // 131072
  const int e = idx >> 10, kk = idx & 1023;
  const int round = kk >> 9, rem = kk & 511, d = rem >> 4, cp = rem & 15;
  const int c = round * 16 + cp;
  WT[idx] = (__bf16)Wout[(size_t)(c * 32 + d) * CZ + e];
}

// ---------------------------------------------------------------------------
__global__ __launch_bounds__(256) void prep_norm(const float* __restrict__ mask,
                                                 float* __restrict__ rnorm) {
  __shared__ float mi[512];
  const int i = blockIdx.x, t = threadIdx.x;
  mi[t]       = mask[(size_t)t * NT + i];
  mi[t + 256] = mask[(size_t)(t + 256) * NT + i];
  __syncthreads();
  for (int j = t; j < NT; j += 256) {
    float acc = 0.f;
#pragma unroll 4
    for (int s = 0; s < NS; ++s) acc += mi[s] * mask[(size_t)s * NT + j];
    rnorm[(size_t)i * NT + j] = 1.0f / (acc + 0.001f);
  }
}

// ---------------------------------------------------------------------------
// LN + projections, writing the tiled layouts. One wave per (i, 64-s chunk).
// LDS: bf16 transpose buffer T aliases the fp32 tile (single-wave block;
// explicit __syncthreads() fences the type-punned overwrite).
// ---------------------------------------------------------------------------
__global__ __launch_bounds__(64) void ln_proj(const float* __restrict__ feat,
                                              const float* __restrict__ mask,
                                              const float* __restrict__ gamma,
                                              const float* __restrict__ beta,
                                              const float* __restrict__ Wa,
                                              const float* __restrict__ Wb,
                                              __bf16* __restrict__ Abf,
                                              __bf16* __restrict__ Bbf) {
  __shared__ __align__(16) float ubuf[64 * 65];    // fp32 tile, row stride 65
  __bf16* T = (__bf16*)ubuf;                       // alias: 32*72 bf16 = 4608 B
  const int bid = blockIdx.x;    // 3072
  const int i = bid >> 3;
  const int s0 = (bid & 7) << 6;
  const int lane = threadIdx.x;
  const int l31 = lane & 31, lh = lane >> 5;

  const int rsub = lane >> 4, cb = (lane & 15) * 4;
#pragma unroll
  for (int rr = 0; rr < 16; ++rr) {
    const int row = rr * 4 + rsub;
    const float4 v = *(const float4*)(feat + ((size_t)(s0 + row) * NT + i) * 64 + cb);
    ubuf[row * 65 + cb] = v.x; ubuf[row * 65 + cb + 1] = v.y;
    ubuf[row * 65 + cb + 2] = v.z; ubuf[row * 65 + cb + 3] = v.w;
  }
  __syncthreads();

  float x[64];
#pragma unroll
  for (int k = 0; k < 64; ++k) x[k] = ubuf[lane * 65 + k];  // lane = s-row

  float mu = 0.f;
#pragma unroll
  for (int k = 0; k < 64; ++k) mu += x[k];
  mu *= (1.0f / 64.0f);
  float var = 0.f;
#pragma unroll
  for (int k = 0; k < 64; ++k) { const float d = x[k] - mu; var += d * d; }
  var *= (1.0f / 64.0f);
  const float rstd = rsqrtf(var + 1e-5f);
#pragma unroll
  for (int k = 0; k < 64; ++k)
    x[k] = (x[k] - mu) * rstd * gamma[k] + beta[k];

  const float mv = mask[(size_t)(s0 + lane) * NT + i];

  // ---- projection A ----
  float acc[32];
#pragma unroll
  for (int c = 0; c < 32; ++c) acc[c] = 0.f;
#pragma unroll 8
  for (int k = 0; k < 64; ++k) {
    const float mk = x[k];
#pragma unroll
    for (int c = 0; c < 32; ++c) acc[c] = fmaf(mk, Wa[k * 32 + c], acc[c]);
  }
  __syncthreads();  // fence: all fp32 tile reads complete before T overwrites it
#pragma unroll
  for (int c = 0; c < 32; ++c) T[c * 72 + lane] = (__bf16)(acc[c] * mv);
  __syncthreads();
  {
    // dest: rb=i>>2, r=(i&3)*32+c, kc = s0/8 + kc_loc, e = s&7
    __bf16* dst = Abf + (size_t)(i >> 2) * 65536 + (size_t)(s0 >> 3) * 1024 +
                  (size_t)((i & 3) * 32) * 8;
#pragma unroll
    for (int q = 0; q < 4; ++q) {
      const bf16x8 v = *(const bf16x8*)(T + l31 * 72 + (q * 2 + lh) * 8);
      *(bf16x8*)(dst + (size_t)(q * 2 + lh) * 1024 + l31 * 8) = v;
    }
  }
  __syncthreads();

  // ---- projection B ----
#pragma unroll
  for (int c = 0; c < 32; ++c) acc[c] = 0.f;
#pragma unroll 8
  for (int k = 0; k < 64; ++k) {
    const float mk = x[k];
#pragma unroll
    for (int c = 0; c < 32; ++c) acc[c] = fmaf(mk, Wb[k * 32 + c], acc[c]);
  }
#pragma unroll
  for (int c = 0; c < 32; ++c) T[c * 72 + lane] = (__bf16)(acc[c] * mv);
  __syncthreads();
  {
    __bf16* dst = Bbf + (size_t)(i >> 3) * 131072 + (size_t)(s0 >> 3) * 2048 +
                  (size_t)((i & 7) * 32) * 8;
#pragma unroll
    for (int q = 0; q < 4; ++q) {
      const bf16x8 v = *(const bf16x8*)(T + l31 * 72 + (q * 2 + lh) * 8);
      *(bf16x8*)(dst + (size_t)(q * 2 + lh) * 2048 + l31 * 8) = v;
    }
  }
}

// ---------------------------------------------------------------------------
// Fused GEMM. ROUND-7 CHANGE: A operands load DIRECTLY global->VGPR (A panel
// is XCD-L2-resident, 1.5 MB under bm%8 mapping); only B goes through LDS.
//   - af fragments have zero lgkmcnt dependency; their vmcnt wait is counted
//     (2 newer B-DMAs stay outstanding), and the compiler may legally hoist
//     af loads across the barrier (global reads can't race LDS staging) --
//     prefetch the LDS path structurally forbids.
//   - per-CU LDS read traffic -33%, DMA drain mass per barrier -33%.
//   - Cost: A read 4x redundantly from L2 (~+7.7 TB/s, total ~20/34.5 TB/s).
// Geometry kept from r6 (proven best): 128x256 block, 8 waves of 64x64,
// acc 2x2x16 = 64 AGPR, ~124 total regs -> 4 waves/SIMD, 2 blocks/CU.
// LDS 41.5 KB: 2 x 16 KB B buffers; epilogue P aliases (20736 elems).
// NT stores REVERTED (r6: WRITE 73.7->99 MB, NT defeats L2 write-coalescing).
// Grid 96x48 bm-major (XCD=bm%8, A L2-resident, FETCH ~100 MB).
// ---------------------------------------------------------------------------
__global__ __launch_bounds__(512, 4) void opm_gemm(const __bf16* __restrict__ A,
                                                   const __bf16* __restrict__ B,
                                                   const __bf16* __restrict__ WT,
                                                   const float* __restrict__ bout,
                                                   const float* __restrict__ rnorm,
                                                   float* __restrict__ out) {
  __shared__ __align__(16) __bf16 smem[20736];  // 41472 B
  // buffer b: Bs = smem + b*8192 (4 kc x 256 r x 8 e)
  // epilogue alias: P[p][d][c'] at p*648 + d*20 + c', p<32 (20736 elems)

  const int tid = threadIdx.x, lane = tid & 63, wid = tid >> 6;
  const int wm = wid & 1, wn = wid >> 1;         // 2 x 4 wave grid, wave 64x64
  const int l31 = lane & 31, lh = lane >> 5;
  const int l15 = lane & 15, lq = lane >> 4;     // epilogue 16x16 indexing
  const int bm = blockIdx.x % 96, bn = blockIdx.x / 96;

  const __bf16* Apan = A + (size_t)bm * 65536;
  const __bf16* Bpan = B + (size_t)bn * 131072;

  floatx16 acc[2][2];
#pragma unroll
  for (int fm = 0; fm < 2; ++fm)
#pragma unroll
    for (int fn = 0; fn < 2; ++fn)
#pragma unroll
      for (int q = 0; q < 16; ++q) acc[fm][fn][q] = 0.f;

  // B staging only: 16 KB/kt = 16 x 1KB loads, 2 per wave.
#define STAGE(kt, OFF)                                                          \
  {                                                                             \
    __bf16* dst = smem + (OFF);                                                 \
    _Pragma("unroll")                                                           \
    for (int q = 0; q < 2; ++q) {                                               \
      const int g = q * 8 + wid;                                                \
      __builtin_amdgcn_global_load_lds(                                         \
          (const __attribute__((address_space(1))) void*)(Bpan +                \
              (size_t)(kt) * 8192 + g * 512 + lane * 8),                        \
          (__attribute__((address_space(3))) void*)(dst + g * 512),             \
          16, 0, 0);                                                            \
    }                                                                           \
  }

  STAGE(0, 0);
  int buf = 0;
  for (int kt = 0; kt < 16; ++kt) {
    __syncthreads();                    // drains stage loads of buf
    if (kt < 15) STAGE(kt + 1, (buf ^ 1) * 8192);
    const __bf16* Ag = Apan + (size_t)kt * 4096;  // A direct from global (L2)
    const __bf16* Bs = smem + buf * 8192;
    __builtin_amdgcn_s_setprio(1);
#pragma unroll
    for (int ks = 0; ks < 2; ++ks) {
      const int ck = ks * 2 + lh;
      bf16x8 af[2], bfv[2];
#pragma unroll
      for (int fm = 0; fm < 2; ++fm)
        af[fm] = *(const bf16x8*)(Ag + ck * 1024 + (wm * 64 + fm * 32 + l31) * 8);
#pragma unroll
      for (int fn = 0; fn < 2; ++fn)
        bfv[fn] = *(const bf16x8*)(Bs + ck * 2048 + (wn * 64 + fn * 32 + l31) * 8);
#pragma unroll
      for (int fm = 0; fm < 2; ++fm)
#pragma unroll
        for (int fn = 0; fn < 2; ++fn)
          acc[fm][fn] = __builtin_amdgcn_mfma_f32_32x32x16_bf16(af[fm], bfv[fn],
                                                                acc[fm][fn], 0, 0, 0);
    }
    __builtin_amdgcn_s_setprio(0);
    buf ^= 1;
  }
#undef STAGE

  // ---- epilogue: 2 rounds over c-halves, z accumulates over rounds ----
  // Wave owns e-slice [wid*16, +16) and ALL 32 p rows (2 p-frags).
  floatx4 zf[2];
#pragma unroll
  for (int ps = 0; ps < 2; ++ps)
#pragma unroll
    for (int q = 0; q < 4; ++q) zf[ps][q] = 0.f;
  const int e0 = wid * 16;

#pragma unroll
  for (int round = 0; round < 2; ++round) {
    __syncthreads();  // main-loop reads / previous GEMM2 reads complete
    // scatter: p = (wm*2+fm)*8 + wn*2+fn; P[p][d=l31][c'], d-stride 20,
    // c' = 8*qp + 4*lh + j  (c = 16*round + c', acc reg = round*8+qp*4+j)
#pragma unroll
    for (int fm = 0; fm < 2; ++fm)
#pragma unroll
      for (int fn = 0; fn < 2; ++fn) {
        const int p = (wm * 2 + fm) * 8 + wn * 2 + fn;
        __bf16* base = smem + p * 648 + l31 * 20 + lh * 4;
#pragma unroll
        for (int qp = 0; qp < 2; ++qp) {
          bf16x4 v;
#pragma unroll
          for (int j = 0; j < 4; ++j)
            v[j] = (__bf16)acc[fm][fn][round * 8 + qp * 4 + j];
          *(bf16x4*)(base + qp * 8) = v;
        }
      }
    __syncthreads();
    // GEMM2 (16x16x32): z[p][e] += P[p][k] * WT[e][round*512+k], K=512.
    // k = ks*32 + lq*8: P addr = row*648 + ks*40 + (lq>>1)*20 + (lq&1)*8.
    const int pAddr = (lq >> 1) * 20 + (lq & 1) * 8;
    const __bf16* p0 = smem + l15 * 648 + pAddr;
    const __bf16* p1 = p0 + 16 * 648;
    const __bf16* w0 = WT + (size_t)(e0 + l15) * 1024 + round * 512 + lq * 8;
#pragma unroll 4
    for (int ks = 0; ks < 16; ++ks) {
      const bf16x8 pa0 = *(const bf16x8*)(p0 + ks * 40);
      const bf16x8 pa1 = *(const bf16x8*)(p1 + ks * 40);
      const bf16x8 wb = *(const bf16x8*)(w0 + ks * 32);
      zf[0] = __builtin_amdgcn_mfma_f32_16x16x32_bf16(pa0, wb, zf[0], 0, 0, 0);
      zf[1] = __builtin_amdgcn_mfma_f32_16x16x32_bf16(pa1, wb, zf[1], 0, 0, 0);
    }
  }

  // out[i][j][e] = (z + bout[e]) * rnorm[i][j]; D-frag: row p = ps*16+lq*4+q,
  // col e = e0 + l15. Plain stores (NT reverted: r6 WRITE 73.7->99 MB).
  {
    const int e = e0 + l15;
    const float be = bout[e];
#pragma unroll
    for (int ps = 0; ps < 2; ++ps)
#pragma unroll
      for (int q = 0; q < 4; ++q) {
        const int p = ps * 16 + lq * 4 + q;
        const int i = bm * 4 + (p >> 3), j = bn * 8 + (p & 7);
        const float rn = rnorm[(size_t)i * NT + j];
        out[((size_t)i * NT + j) * CZ + e] = (zf[ps][q] + be) * rn;
      }
  }
}

// ---------------------------------------------------------------------------
extern "C" void kernel_launch(void* const* d_in, const int* in_sizes, int n_in,
                              void* d_out, int out_size, void* d_ws, size_t ws_size,
                              hipStream_t stream) {
  const float* feat  = (const float*)d_in[0];
  const float* mask  = (const float*)d_in[1];
  const float* gamma = (const float*)d_in[2];
  const float* beta  = (const float*)d_in[3];
  const float* Wa    = (const float*)d_in[4];
  const float* Wb    = (const float*)d_in[5];
  const float* Wout  = (const float*)d_in[6];
  const float* bout  = (const float*)d_in[7];
  float* out = (float*)d_out;

  char* ws = (char*)d_ws;
  const size_t AB_BYTES = (size_t)96 * 65536 * sizeof(__bf16);  // 12,582,912
  __bf16* Abf = (__bf16*)(ws);
  __bf16* Bbf = (__bf16*)(ws + AB_BYTES);
  __bf16* WT  = (__bf16*)(ws + 2 * AB_BYTES);
  float* rnorm = (float*)(ws + 2 * AB_BYTES + (size_t)CZ * 1024 * sizeof(__bf16));

  prep_wout<<<512, 256, 0, stream>>>(Wout, WT);
  prep_norm<<<NT, 256, 0, stream>>>(mask, rnorm);
  ln_proj<<<NT * (NS / 64), 64, 0, stream>>>(feat, mask, gamma, beta, Wa, Wb, Abf, Bbf);
  opm_gemm<<<96 * 48, 512, 0, stream>>>(Abf, Bbf, WT, bout, rnorm, out);
}

// Round 8
// 424.979 us; speedup vs baseline: 1.1085x; 1.1085x over previous
//
#include <hip/hip_runtime.h>
#include <cstdint>
#include <cstddef>

#define NS 512
#define NT 384
#define CZ 128

typedef __bf16 bf16x8 __attribute__((ext_vector_type(8)));
typedef __bf16 bf16x4 __attribute__((ext_vector_type(4)));
typedef float floatx16 __attribute__((ext_vector_type(16)));
typedef float floatx4 __attribute__((ext_vector_type(4)));

// Workspace layouts (bf16 element units):
//   A_t[rb(96)][kc(64)][r(128)][e(8)]   panel = 65536 elems (128 rows, k=s)
//   B_t[pb(48)][kc(64)][r(256)][e(8)]   panel = 131072 elems
//   WT [e(128)][k(1024)]  k = (c>>4)*512 + d*16 + (c&15)
// k index = s;  kc = s>>3, e = s&7.  A-row m = i*32+c, B-row n = j*32+d.

// ---------------------------------------------------------------------------
__global__ __launch_bounds__(256) void prep_wout(const float* __restrict__ Wout,
                                                 __bf16* __restrict__ WT) {
  const int idx = blockIdx.x * 256 + threadIdx.x;  // 131072
  const int e = idx >> 10, kk = idx & 1023;
  const int round = kk >> 9, rem = kk & 511, d = rem >> 4, cp = rem & 15;
  const int c = round * 16 + cp;
  WT[idx] = (__bf16)Wout[(size_t)(c * 32 + d) * CZ + e];
}

// ---------------------------------------------------------------------------
__global__ __launch_bounds__(256) void prep_norm(const float* __restrict__ mask,
                                                 float* __restrict__ rnorm) {
  __shared__ float mi[512];
  const int i = blockIdx.x, t = threadIdx.x;
  mi[t]       = mask[(size_t)t * NT + i];
  mi[t + 256] = mask[(size_t)(t + 256) * NT + i];
  __syncthreads();
  for (int j = t; j < NT; j += 256) {
    float acc = 0.f;
#pragma unroll 4
    for (int s = 0; s < NS; ++s) acc += mi[s] * mask[(size_t)s * NT + j];
    rnorm[(size_t)i * NT + j] = 1.0f / (acc + 0.001f);
  }
}

// ---------------------------------------------------------------------------
// LN + projections. ROUND-8 CHANGE: no LDS tile round-trip. Each lane loads
// its own s-row of feat directly (64 contiguous floats = 16 x float4; every
// fetched line fully used, lane stride NT*64*4 B). Deletes the 16.6 KB fp32
// ubuf, two barriers, and an LDS write+read pass. LDS = T only (4608 B) ->
// blocks/CU rise 9 -> reg-limited (~16); all 12 needed blocks resident.
// ---------------------------------------------------------------------------
__global__ __launch_bounds__(64) void ln_proj(const float* __restrict__ feat,
                                              const float* __restrict__ mask,
                                              const float* __restrict__ gamma,
                                              const float* __restrict__ beta,
                                              const float* __restrict__ Wa,
                                              const float* __restrict__ Wb,
                                              __bf16* __restrict__ Abf,
                                              __bf16* __restrict__ Bbf) {
  __shared__ __align__(16) __bf16 T[32 * 72];  // transpose buffer, stride 72
  const int bid = blockIdx.x;    // 3072
  const int i = bid >> 3;
  const int s0 = (bid & 7) << 6;
  const int lane = threadIdx.x;
  const int l31 = lane & 31, lh = lane >> 5;

  // Direct per-lane row load: lane owns s-row (s0+lane), all 64 channels.
  const float* frow = feat + ((size_t)(s0 + lane) * NT + i) * 64;
  float x[64];
#pragma unroll
  for (int q = 0; q < 16; ++q) {
    const float4 v = *(const float4*)(frow + q * 4);
    x[q * 4 + 0] = v.x; x[q * 4 + 1] = v.y;
    x[q * 4 + 2] = v.z; x[q * 4 + 3] = v.w;
  }

  float mu = 0.f;
#pragma unroll
  for (int k = 0; k < 64; ++k) mu += x[k];
  mu *= (1.0f / 64.0f);
  float var = 0.f;
#pragma unroll
  for (int k = 0; k < 64; ++k) { const float d = x[k] - mu; var += d * d; }
  var *= (1.0f / 64.0f);
  const float rstd = rsqrtf(var + 1e-5f);
#pragma unroll
  for (int k = 0; k < 64; ++k)
    x[k] = (x[k] - mu) * rstd * gamma[k] + beta[k];

  const float mv = mask[(size_t)(s0 + lane) * NT + i];

  // ---- projection A ----
  float acc[32];
#pragma unroll
  for (int c = 0; c < 32; ++c) acc[c] = 0.f;
#pragma unroll 8
  for (int k = 0; k < 64; ++k) {
    const float mk = x[k];
#pragma unroll
    for (int c = 0; c < 32; ++c) acc[c] = fmaf(mk, Wa[k * 32 + c], acc[c]);
  }
#pragma unroll
  for (int c = 0; c < 32; ++c) T[c * 72 + lane] = (__bf16)(acc[c] * mv);
  __syncthreads();
  {
    // dest: rb=i>>2, r=(i&3)*32+c, kc = s0/8 + kc_loc, e = s&7
    __bf16* dst = Abf + (size_t)(i >> 2) * 65536 + (size_t)(s0 >> 3) * 1024 +
                  (size_t)((i & 3) * 32) * 8;
#pragma unroll
    for (int q = 0; q < 4; ++q) {
      const bf16x8 v = *(const bf16x8*)(T + l31 * 72 + (q * 2 + lh) * 8);
      *(bf16x8*)(dst + (size_t)(q * 2 + lh) * 1024 + l31 * 8) = v;
    }
  }
  __syncthreads();

  // ---- projection B ----
#pragma unroll
  for (int c = 0; c < 32; ++c) acc[c] = 0.f;
#pragma unroll 8
  for (int k = 0; k < 64; ++k) {
    const float mk = x[k];
#pragma unroll
    for (int c = 0; c < 32; ++c) acc[c] = fmaf(mk, Wb[k * 32 + c], acc[c]);
  }
#pragma unroll
  for (int c = 0; c < 32; ++c) T[c * 72 + lane] = (__bf16)(acc[c] * mv);
  __syncthreads();
  {
    __bf16* dst = Bbf + (size_t)(i >> 3) * 131072 + (size_t)(s0 >> 3) * 2048 +
                  (size_t)((i & 7) * 32) * 8;
#pragma unroll
    for (int q = 0; q < 4; ++q) {
      const bf16x8 v = *(const bf16x8*)(T + l31 * 72 + (q * 2 + lh) * 8);
      *(bf16x8*)(dst + (size_t)(q * 2 + lh) * 2048 + l31 * 8) = v;
    }
  }
}

// ---------------------------------------------------------------------------
// Fused GEMM. ROUND-8: exact r6 structure (best measured: 247 us, MfmaUtil
// 35.6, 4 waves/SIMD) with plain stores (r6's nontemporal rider pushed
// WRITE 73.7->99 MB by defeating L2 write-coalescing of 64 B partial lines).
// r7 lesson: A must stay in LDS (direct-from-L2 af loads put VMEM latency on
// the MFMA critical path and intertwine with B-DMA vmcnt: 247->305 us).
// Geometry: 128x256 block, 8 waves of 64x64, acc 2x2x16 = 64 AGPR,
// __launch_bounds__(512,4) -> 2 blocks/CU, 4 waves/SIMD.
// Grid 96x48 bm-major (XCD=bm%8, A L2-resident, FETCH ~100 MB).
// ---------------------------------------------------------------------------
__global__ __launch_bounds__(512, 4) void opm_gemm(const __bf16* __restrict__ A,
                                                   const __bf16* __restrict__ B,
                                                   const __bf16* __restrict__ WT,
                                                   const float* __restrict__ bout,
                                                   const float* __restrict__ rnorm,
                                                   float* __restrict__ out) {
  __shared__ __align__(16) __bf16 smem[24576];  // 49152 B
  // buffer b: As = smem + b*12288 (4 kc x 128 r x 8 e), Bs = As + 4096 (4x256x8)
  // epilogue alias: P[p][d][c'] at p*648 + d*20 + c', p<32 (20736 elems)

  const int tid = threadIdx.x, lane = tid & 63, wid = tid >> 6;
  const int wm = wid & 1, wn = wid >> 1;         // 2 x 4 wave grid, wave 64x64
  const int l31 = lane & 31, lh = lane >> 5;
  const int l15 = lane & 15, lq = lane >> 4;     // epilogue 16x16 indexing
  const int bm = blockIdx.x % 96, bn = blockIdx.x / 96;

  const __bf16* Apan = A + (size_t)bm * 65536;
  const __bf16* Bpan = B + (size_t)bn * 131072;

  floatx16 acc[2][2];
#pragma unroll
  for (int fm = 0; fm < 2; ++fm)
#pragma unroll
    for (int fn = 0; fn < 2; ++fn)
#pragma unroll
      for (int q = 0; q < 16; ++q) acc[fm][fn][q] = 0.f;

  // Staging: 24 KB/kt. A chunk 4096 elems: wave w loads 512 elems (1 inst).
  // B chunk 8192 elems: wave w loads chunks q*8+w (2 insts). 3 insts/wave.
#define STAGE(kt, OFF)                                                          \
  {                                                                             \
    __bf16* dst = smem + (OFF);                                                 \
    __builtin_amdgcn_global_load_lds(                                           \
        (const __attribute__((address_space(1))) void*)(Apan +                  \
            (size_t)(kt) * 4096 + wid * 512 + lane * 8),                        \
        (__attribute__((address_space(3))) void*)(dst + wid * 512), 16, 0, 0);  \
    _Pragma("unroll")                                                           \
    for (int q = 0; q < 2; ++q) {                                               \
      const int g = q * 8 + wid;                                                \
      __builtin_amdgcn_global_load_lds(                                         \
          (const __attribute__((address_space(1))) void*)(Bpan +                \
              (size_t)(kt) * 8192 + g * 512 + lane * 8),                        \
          (__attribute__((address_space(3))) void*)(dst + 4096 + g * 512),      \
          16, 0, 0);                                                            \
    }                                                                           \
  }

  STAGE(0, 0);
  int buf = 0;
  for (int kt = 0; kt < 16; ++kt) {
    __syncthreads();                    // drains stage loads of buf
    if (kt < 15) STAGE(kt + 1, (buf ^ 1) * 12288);
    const __bf16* As = smem + buf * 12288;
    const __bf16* Bs = As + 4096;
    __builtin_amdgcn_s_setprio(1);
#pragma unroll
    for (int ks = 0; ks < 2; ++ks) {
      const int ck = ks * 2 + lh;
      bf16x8 af[2], bfv[2];
#pragma unroll
      for (int fm = 0; fm < 2; ++fm)
        af[fm] = *(const bf16x8*)(As + ck * 1024 + (wm * 64 + fm * 32 + l31) * 8);
#pragma unroll
      for (int fn = 0; fn < 2; ++fn)
        bfv[fn] = *(const bf16x8*)(Bs + ck * 2048 + (wn * 64 + fn * 32 + l31) * 8);
#pragma unroll
      for (int fm = 0; fm < 2; ++fm)
#pragma unroll
        for (int fn = 0; fn < 2; ++fn)
          acc[fm][fn] = __builtin_amdgcn_mfma_f32_32x32x16_bf16(af[fm], bfv[fn],
                                                                acc[fm][fn], 0, 0, 0);
    }
    __builtin_amdgcn_s_setprio(0);
    buf ^= 1;
  }
#undef STAGE

  // ---- epilogue: 2 rounds over c-halves, z accumulates over rounds ----
  // Wave owns e-slice [wid*16, +16) and ALL 32 p rows (2 p-frags).
  floatx4 zf[2];
#pragma unroll
  for (int ps = 0; ps < 2; ++ps)
#pragma unroll
    for (int q = 0; q < 4; ++q) zf[ps][q] = 0.f;
  const int e0 = wid * 16;

#pragma unroll
  for (int round = 0; round < 2; ++round) {
    __syncthreads();  // main-loop reads / previous GEMM2 reads complete
    // scatter: p = (wm*2+fm)*8 + wn*2+fn; P[p][d=l31][c'], d-stride 20,
    // c' = 8*qp + 4*lh + j  (c = 16*round + c', acc reg = round*8+qp*4+j)
#pragma unroll
    for (int fm = 0; fm < 2; ++fm)
#pragma unroll
      for (int fn = 0; fn < 2; ++fn) {
        const int p = (wm * 2 + fm) * 8 + wn * 2 + fn;
        __bf16* base = smem + p * 648 + l31 * 20 + lh * 4;
#pragma unroll
        for (int qp = 0; qp < 2; ++qp) {
          bf16x4 v;
#pragma unroll
          for (int j = 0; j < 4; ++j)
            v[j] = (__bf16)acc[fm][fn][round * 8 + qp * 4 + j];
          *(bf16x4*)(base + qp * 8) = v;
        }
      }
    __syncthreads();
    // GEMM2 (16x16x32): z[p][e] += P[p][k] * WT[e][round*512+k], K=512.
    // k = ks*32 + lq*8: P addr = row*648 + ks*40 + (lq>>1)*20 + (lq&1)*8.
    const int pAddr = (lq >> 1) * 20 + (lq & 1) * 8;
    const __bf16* p0 = smem + l15 * 648 + pAddr;
    const __bf16* p1 = p0 + 16 * 648;
    const __bf16* w0 = WT + (size_t)(e0 + l15) * 1024 + round * 512 + lq * 8;
#pragma unroll 4
    for (int ks = 0; ks < 16; ++ks) {
      const bf16x8 pa0 = *(const bf16x8*)(p0 + ks * 40);
      const bf16x8 pa1 = *(const bf16x8*)(p1 + ks * 40);
      const bf16x8 wb = *(const bf16x8*)(w0 + ks * 32);
      zf[0] = __builtin_amdgcn_mfma_f32_16x16x32_bf16(pa0, wb, zf[0], 0, 0, 0);
      zf[1] = __builtin_amdgcn_mfma_f32_16x16x32_bf16(pa1, wb, zf[1], 0, 0, 0);
    }
  }

  // out[i][j][e] = (z + bout[e]) * rnorm[i][j]; D-frag: row p = ps*16+lq*4+q,
  // col e = e0 + l15. Plain stores (L2 write-coalescing of partial lines).
  {
    const int e = e0 + l15;
    const float be = bout[e];
#pragma unroll
    for (int ps = 0; ps < 2; ++ps)
#pragma unroll
      for (int q = 0; q < 4; ++q) {
        const int p = ps * 16 + lq * 4 + q;
        const int i = bm * 4 + (p >> 3), j = bn * 8 + (p & 7);
        const float rn = rnorm[(size_t)i * NT + j];
        out[((size_t)i * NT + j) * CZ + e] = (zf[ps][q] + be) * rn;
      }
  }
}

// ---------------------------------------------------------------------------
extern "C" void kernel_launch(void* const* d_in, const int* in_sizes, int n_in,
                              void* d_out, int out_size, void* d_ws, size_t ws_size,
                              hipStream_t stream) {
  const float* feat  = (const float*)d_in[0];
  const float* mask  = (const float*)d_in[1];
  const float* gamma = (const float*)d_in[2];
  const float* beta  = (const float*)d_in[3];
  const float* Wa    = (const float*)d_in[4];
  const float* Wb    = (const float*)d_in[5];
  const float* Wout  = (const float*)d_in[6];
  const float* bout  = (const float*)d_in[7];
  float* out = (float*)d_out;

  char* ws = (char*)d_ws;
  const size_t AB_BYTES = (size_t)96 * 65536 * sizeof(__bf16);  // 12,582,912
  __bf16* Abf = (__bf16*)(ws);
  __bf16* Bbf = (__bf16*)(ws + AB_BYTES);
  __bf16* WT  = (__bf16*)(ws + 2 * AB_BYTES);
  float* rnorm = (float*)(ws + 2 * AB_BYTES + (size_t)CZ * 1024 * sizeof(__bf16));

  prep_wout<<<512, 256, 0, stream>>>(Wout, WT);
  prep_norm<<<NT, 256, 0, stream>>>(mask, rnorm);
  ln_proj<<<NT * (NS / 64), 64, 0, stream>>>(feat, mask, gamma, beta, Wa, Wb, Abf, Bbf);
  opm_gemm<<<96 * 48, 512, 0, stream>>>(Abf, Bbf, WT, bout, rnorm, out);
}

// Round 9
// 378.096 us; speedup vs baseline: 1.2459x; 1.1240x over previous
//
#include <hip/hip_runtime.h>
#include <cstdint>
#include <cstddef>

#define NS 512
#define NT 384
#define CZ 128

typedef __bf16 bf16x8 __attribute__((ext_vector_type(8)));
typedef __bf16 bf16x4 __attribute__((ext_vector_type(4)));
typedef float floatx16 __attribute__((ext_vector_type(16)));
typedef float floatx4 __attribute__((ext_vector_type(4)));

// Workspace layouts (bf16 element units):
//   A_t[rb(96)][kc(64)][r(128)][e(8)]   panel = 65536 elems (128 rows, k=s)
//   B_t[pb(48)][kc(64)][r(256)][e(8)]   panel = 131072 elems
//   WT [e(128)][k(1024)]  k = (c>>4)*512 + d*16 + (c&15)
//   MT [j(384)][s(512)] bf16 transposed mask — ALIASES the Abf region
//   (consumed by prep_norm2 before ln_proj overwrites Abf; same stream).
// k index = s;  kc = s>>3, e = s&7.  A-row m = i*32+c, B-row n = j*32+d.

// ---------------------------------------------------------------------------
__global__ __launch_bounds__(256) void prep_wout(const float* __restrict__ Wout,
                                                 __bf16* __restrict__ WT) {
  const int idx = blockIdx.x * 256 + threadIdx.x;  // 131072
  const int e = idx >> 10, kk = idx & 1023;
  const int round = kk >> 9, rem = kk & 511, d = rem >> 4, cp = rem & 15;
  const int c = round * 16 + cp;
  WT[idx] = (__bf16)Wout[(size_t)(c * 32 + d) * CZ + e];
}

// ---------------------------------------------------------------------------
// Coalesced LDS-transpose: mask[512][384] f32 -> MT[384][512] bf16.
// 8 s-tiles x 6 j-tiles = 48 blocks x 256 thr. 0/1 mask values exact in bf16.
// ---------------------------------------------------------------------------
__global__ __launch_bounds__(256) void prep_maskT(const float* __restrict__ mask,
                                                  __bf16* __restrict__ MT) {
  __shared__ __bf16 TT[64 * 72];  // TT[j_local][s_local], stride 72 (16B-align)
  const int s0 = (blockIdx.x & 7) * 64, j0 = (blockIdx.x >> 3) * 64;
  const int t = threadIdx.x;
  const int row = t >> 4, col0 = (t & 15) * 4;
#pragma unroll
  for (int rr = 0; rr < 4; ++rr) {
    const int r = rr * 16 + row;  // s_local
    const float4 v = *(const float4*)(mask + (size_t)(s0 + r) * NT + j0 + col0);
    TT[(col0 + 0) * 72 + r] = (__bf16)v.x;
    TT[(col0 + 1) * 72 + r] = (__bf16)v.y;
    TT[(col0 + 2) * 72 + r] = (__bf16)v.z;
    TT[(col0 + 3) * 72 + r] = (__bf16)v.w;
  }
  __syncthreads();
#pragma unroll
  for (int h = 0; h < 2; ++h) {
    const int jr = h * 32 + (t >> 3), sc = (t & 7) * 8;
    *(bf16x8*)(MT + (size_t)(j0 + jr) * 512 + s0 + sc) =
        *(const bf16x8*)(TT + jr * 72 + sc);
  }
}

// ---------------------------------------------------------------------------
// rnorm[i][j] = 1/((M^T M)[i,j] + 0.001) via MFMA over MT (K=512).
// 12x12 = 144 blocks x 1 wave, 32x32 tile each, 32 x mfma_32x32x16_bf16.
// Replaces the old 75M stride-1536B scalar-load version (~4.8 GB of L2 line
// traffic ~ 100+ us) with ~0.6M contiguous 16B loads on an L2-resident 384 KB
// operand. fp32 accumulation => bit-exact for 0/1 masks.
// ---------------------------------------------------------------------------
__global__ __launch_bounds__(64) void prep_norm2(const __bf16* __restrict__ MT,
                                                 float* __restrict__ rnorm) {
  const int i0 = (blockIdx.x % 12) * 32, j0 = (blockIdx.x / 12) * 32;
  const int lane = threadIdx.x, l31 = lane & 31, lh = lane >> 5;
  floatx16 acc;
#pragma unroll
  for (int q = 0; q < 16; ++q) acc[q] = 0.f;
  // A-frag row = i0+l31 (k = kc*16 + lh*8 + e), B-frag row = j0+l31.
  const __bf16* arow = MT + (size_t)(i0 + l31) * 512 + lh * 8;
  const __bf16* brow = MT + (size_t)(j0 + l31) * 512 + lh * 8;
#pragma unroll 8
  for (int kc = 0; kc < 32; ++kc) {
    const bf16x8 a = *(const bf16x8*)(arow + kc * 16);
    const bf16x8 b = *(const bf16x8*)(brow + kc * 16);
    acc = __builtin_amdgcn_mfma_f32_32x32x16_bf16(a, b, acc, 0, 0, 0);
  }
  // D-frag: A-dim = (r&3) + 4*lh + 8*(r>>2), B-dim = l31 (norm symmetric).
#pragma unroll
  for (int r = 0; r < 16; ++r) {
    const int il = (r & 3) + 4 * lh + 8 * (r >> 2);
    rnorm[(size_t)(i0 + il) * NT + j0 + l31] = 1.0f / (acc[r] + 0.001f);
  }
}

// ---------------------------------------------------------------------------
// LN + projections (r8 structure: direct per-lane row loads, no tile
// round-trip; LDS = 4.6 KB transpose buffer only).
// ---------------------------------------------------------------------------
__global__ __launch_bounds__(64) void ln_proj(const float* __restrict__ feat,
                                              const float* __restrict__ mask,
                                              const float* __restrict__ gamma,
                                              const float* __restrict__ beta,
                                              const float* __restrict__ Wa,
                                              const float* __restrict__ Wb,
                                              __bf16* __restrict__ Abf,
                                              __bf16* __restrict__ Bbf) {
  __shared__ __align__(16) __bf16 T[32 * 72];  // transpose buffer, stride 72
  const int bid = blockIdx.x;    // 3072
  const int i = bid >> 3;
  const int s0 = (bid & 7) << 6;
  const int lane = threadIdx.x;
  const int l31 = lane & 31, lh = lane >> 5;

  // Direct per-lane row load: lane owns s-row (s0+lane), all 64 channels.
  const float* frow = feat + ((size_t)(s0 + lane) * NT + i) * 64;
  float x[64];
#pragma unroll
  for (int q = 0; q < 16; ++q) {
    const float4 v = *(const float4*)(frow + q * 4);
    x[q * 4 + 0] = v.x; x[q * 4 + 1] = v.y;
    x[q * 4 + 2] = v.z; x[q * 4 + 3] = v.w;
  }

  float mu = 0.f;
#pragma unroll
  for (int k = 0; k < 64; ++k) mu += x[k];
  mu *= (1.0f / 64.0f);
  float var = 0.f;
#pragma unroll
  for (int k = 0; k < 64; ++k) { const float d = x[k] - mu; var += d * d; }
  var *= (1.0f / 64.0f);
  const float rstd = rsqrtf(var + 1e-5f);
#pragma unroll
  for (int k = 0; k < 64; ++k)
    x[k] = (x[k] - mu) * rstd * gamma[k] + beta[k];

  const float mv = mask[(size_t)(s0 + lane) * NT + i];

  // ---- projection A ----
  float acc[32];
#pragma unroll
  for (int c = 0; c < 32; ++c) acc[c] = 0.f;
#pragma unroll 8
  for (int k = 0; k < 64; ++k) {
    const float mk = x[k];
#pragma unroll
    for (int c = 0; c < 32; ++c) acc[c] = fmaf(mk, Wa[k * 32 + c], acc[c]);
  }
#pragma unroll
  for (int c = 0; c < 32; ++c) T[c * 72 + lane] = (__bf16)(acc[c] * mv);
  __syncthreads();
  {
    // dest: rb=i>>2, r=(i&3)*32+c, kc = s0/8 + kc_loc, e = s&7
    __bf16* dst = Abf + (size_t)(i >> 2) * 65536 + (size_t)(s0 >> 3) * 1024 +
                  (size_t)((i & 3) * 32) * 8;
#pragma unroll
    for (int q = 0; q < 4; ++q) {
      const bf16x8 v = *(const bf16x8*)(T + l31 * 72 + (q * 2 + lh) * 8);
      *(bf16x8*)(dst + (size_t)(q * 2 + lh) * 1024 + l31 * 8) = v;
    }
  }
  __syncthreads();

  // ---- projection B ----
#pragma unroll
  for (int c = 0; c < 32; ++c) acc[c] = 0.f;
#pragma unroll 8
  for (int k = 0; k < 64; ++k) {
    const float mk = x[k];
#pragma unroll
    for (int c = 0; c < 32; ++c) acc[c] = fmaf(mk, Wb[k * 32 + c], acc[c]);
  }
#pragma unroll
  for (int c = 0; c < 32; ++c) T[c * 72 + lane] = (__bf16)(acc[c] * mv);
  __syncthreads();
  {
    __bf16* dst = Bbf + (size_t)(i >> 3) * 131072 + (size_t)(s0 >> 3) * 2048 +
                  (size_t)((i & 7) * 32) * 8;
#pragma unroll
    for (int q = 0; q < 4; ++q) {
      const bf16x8 v = *(const bf16x8*)(T + l31 * 72 + (q * 2 + lh) * 8);
      *(bf16x8*)(dst + (size_t)(q * 2 + lh) * 2048 + l31 * 8) = v;
    }
  }
}

// ---------------------------------------------------------------------------
// Fused GEMM (r6/r8 structure, best measured: 246 us, MfmaUtil 35.5,
// 4 waves/SIMD, plain stores). Untouched this round.
// Geometry: 128x256 block, 8 waves of 64x64, acc 2x2x16 = 64 AGPR,
// __launch_bounds__(512,4) -> 2 blocks/CU, 4 waves/SIMD.
// Grid 96x48 bm-major (XCD=bm%8, A L2-resident).
// ---------------------------------------------------------------------------
__global__ __launch_bounds__(512, 4) void opm_gemm(const __bf16* __restrict__ A,
                                                   const __bf16* __restrict__ B,
                                                   const __bf16* __restrict__ WT,
                                                   const float* __restrict__ bout,
                                                   const float* __restrict__ rnorm,
                                                   float* __restrict__ out) {
  __shared__ __align__(16) __bf16 smem[24576];  // 49152 B
  // buffer b: As = smem + b*12288 (4 kc x 128 r x 8 e), Bs = As + 4096 (4x256x8)
  // epilogue alias: P[p][d][c'] at p*648 + d*20 + c', p<32 (20736 elems)

  const int tid = threadIdx.x, lane = tid & 63, wid = tid >> 6;
  const int wm = wid & 1, wn = wid >> 1;         // 2 x 4 wave grid, wave 64x64
  const int l31 = lane & 31, lh = lane >> 5;
  const int l15 = lane & 15, lq = lane >> 4;     // epilogue 16x16 indexing
  const int bm = blockIdx.x % 96, bn = blockIdx.x / 96;

  const __bf16* Apan = A + (size_t)bm * 65536;
  const __bf16* Bpan = B + (size_t)bn * 131072;

  floatx16 acc[2][2];
#pragma unroll
  for (int fm = 0; fm < 2; ++fm)
#pragma unroll
    for (int fn = 0; fn < 2; ++fn)
#pragma unroll
      for (int q = 0; q < 16; ++q) acc[fm][fn][q] = 0.f;

  // Staging: 24 KB/kt. A chunk 4096 elems: wave w loads 512 elems (1 inst).
  // B chunk 8192 elems: wave w loads chunks q*8+w (2 insts). 3 insts/wave.
#define STAGE(kt, OFF)                                                          \
  {                                                                             \
    __bf16* dst = smem + (OFF);                                                 \
    __builtin_amdgcn_global_load_lds(                                           \
        (const __attribute__((address_space(1))) void*)(Apan +                  \
            (size_t)(kt) * 4096 + wid * 512 + lane * 8),                        \
        (__attribute__((address_space(3))) void*)(dst + wid * 512), 16, 0, 0);  \
    _Pragma("unroll")                                                           \
    for (int q = 0; q < 2; ++q) {                                               \
      const int g = q * 8 + wid;                                                \
      __builtin_amdgcn_global_load_lds(                                         \
          (const __attribute__((address_space(1))) void*)(Bpan +                \
              (size_t)(kt) * 8192 + g * 512 + lane * 8),                        \
          (__attribute__((address_space(3))) void*)(dst + 4096 + g * 512),      \
          16, 0, 0);                                                            \
    }                                                                           \
  }

  STAGE(0, 0);
  int buf = 0;
  for (int kt = 0; kt < 16; ++kt) {
    __syncthreads();                    // drains stage loads of buf
    if (kt < 15) STAGE(kt + 1, (buf ^ 1) * 12288);
    const __bf16* As = smem + buf * 12288;
    const __bf16* Bs = As + 4096;
    __builtin_amdgcn_s_setprio(1);
#pragma unroll
    for (int ks = 0; ks < 2; ++ks) {
      const int ck = ks * 2 + lh;
      bf16x8 af[2], bfv[2];
#pragma unroll
      for (int fm = 0; fm < 2; ++fm)
        af[fm] = *(const bf16x8*)(As + ck * 1024 + (wm * 64 + fm * 32 + l31) * 8);
#pragma unroll
      for (int fn = 0; fn < 2; ++fn)
        bfv[fn] = *(const bf16x8*)(Bs + ck * 2048 + (wn * 64 + fn * 32 + l31) * 8);
#pragma unroll
      for (int fm = 0; fm < 2; ++fm)
#pragma unroll
        for (int fn = 0; fn < 2; ++fn)
          acc[fm][fn] = __builtin_amdgcn_mfma_f32_32x32x16_bf16(af[fm], bfv[fn],
                                                                acc[fm][fn], 0, 0, 0);
    }
    __builtin_amdgcn_s_setprio(0);
    buf ^= 1;
  }
#undef STAGE

  // ---- epilogue: 2 rounds over c-halves, z accumulates over rounds ----
  // Wave owns e-slice [wid*16, +16) and ALL 32 p rows (2 p-frags).
  floatx4 zf[2];
#pragma unroll
  for (int ps = 0; ps < 2; ++ps)
#pragma unroll
    for (int q = 0; q < 4; ++q) zf[ps][q] = 0.f;
  const int e0 = wid * 16;

#pragma unroll
  for (int round = 0; round < 2; ++round) {
    __syncthreads();  // main-loop reads / previous GEMM2 reads complete
    // scatter: p = (wm*2+fm)*8 + wn*2+fn; P[p][d=l31][c'], d-stride 20,
    // c' = 8*qp + 4*lh + j  (c = 16*round + c', acc reg = round*8+qp*4+j)
#pragma unroll
    for (int fm = 0; fm < 2; ++fm)
#pragma unroll
      for (int fn = 0; fn < 2; ++fn) {
        const int p = (wm * 2 + fm) * 8 + wn * 2 + fn;
        __bf16* base = smem + p * 648 + l31 * 20 + lh * 4;
#pragma unroll
        for (int qp = 0; qp < 2; ++qp) {
          bf16x4 v;
#pragma unroll
          for (int j = 0; j < 4; ++j)
            v[j] = (__bf16)acc[fm][fn][round * 8 + qp * 4 + j];
          *(bf16x4*)(base + qp * 8) = v;
        }
      }
    __syncthreads();
    // GEMM2 (16x16x32): z[p][e] += P[p][k] * WT[e][round*512+k], K=512.
    // k = ks*32 + lq*8: P addr = row*648 + ks*40 + (lq>>1)*20 + (lq&1)*8.
    const int pAddr = (lq >> 1) * 20 + (lq & 1) * 8;
    const __bf16* p0 = smem + l15 * 648 + pAddr;
    const __bf16* p1 = p0 + 16 * 648;
    const __bf16* w0 = WT + (size_t)(e0 + l15) * 1024 + round * 512 + lq * 8;
#pragma unroll 4
    for (int ks = 0; ks < 16; ++ks) {
      const bf16x8 pa0 = *(const bf16x8*)(p0 + ks * 40);
      const bf16x8 pa1 = *(const bf16x8*)(p1 + ks * 40);
      const bf16x8 wb = *(const bf16x8*)(w0 + ks * 32);
      zf[0] = __builtin_amdgcn_mfma_f32_16x16x32_bf16(pa0, wb, zf[0], 0, 0, 0);
      zf[1] = __builtin_amdgcn_mfma_f32_16x16x32_bf16(pa1, wb, zf[1], 0, 0, 0);
    }
  }

  // out[i][j][e] = (z + bout[e]) * rnorm[i][j]; D-frag: row p = ps*16+lq*4+q,
  // col e = e0 + l15. Plain stores (L2 write-coalescing of partial lines).
  {
    const int e = e0 + l15;
    const float be = bout[e];
#pragma unroll
    for (int ps = 0; ps < 2; ++ps)
#pragma unroll
      for (int q = 0; q < 4; ++q) {
        const int p = ps * 16 + lq * 4 + q;
        const int i = bm * 4 + (p >> 3), j = bn * 8 + (p & 7);
        const float rn = rnorm[(size_t)i * NT + j];
        out[((size_t)i * NT + j) * CZ + e] = (zf[ps][q] + be) * rn;
      }
  }
}

// ---------------------------------------------------------------------------
extern "C" void kernel_launch(void* const* d_in, const int* in_sizes, int n_in,
                              void* d_out, int out_size, void* d_ws, size_t ws_size,
                              hipStream_t stream) {
  const float* feat  = (const float*)d_in[0];
  const float* mask  = (const float*)d_in[1];
  const float* gamma = (const float*)d_in[2];
  const float* beta  = (const float*)d_in[3];
  const float* Wa    = (const float*)d_in[4];
  const float* Wb    = (const float*)d_in[5];
  const float* Wout  = (const float*)d_in[6];
  const float* bout  = (const float*)d_in[7];
  float* out = (float*)d_out;

  char* ws = (char*)d_ws;
  const size_t AB_BYTES = (size_t)96 * 65536 * sizeof(__bf16);  // 12,582,912
  __bf16* Abf = (__bf16*)(ws);
  __bf16* Bbf = (__bf16*)(ws + AB_BYTES);
  __bf16* WT  = (__bf16*)(ws + 2 * AB_BYTES);
  float* rnorm = (float*)(ws + 2 * AB_BYTES + (size_t)CZ * 1024 * sizeof(__bf16));
  // MT aliases Abf: fully consumed by prep_norm2 before ln_proj writes Abf
  // (same-stream ordering guarantees sequencing).
  __bf16* MT = (__bf16*)(ws);

  prep_wout<<<512, 256, 0, stream>>>(Wout, WT);
  prep_maskT<<<48, 256, 0, stream>>>(mask, MT);
  prep_norm2<<<144, 64, 0, stream>>>(MT, rnorm);
  ln_proj<<<NT * (NS / 64), 64, 0, stream>>>(feat, mask, gamma, beta, Wa, Wb, Abf, Bbf);
  opm_gemm<<<96 * 48, 512, 0, stream>>>(Abf, Bbf, WT, bout, rnorm, out);
}